// Round 1
// baseline (600.227 us; speedup 1.0000x reference)
//
#include <hip/hip_runtime.h>

// x: [8, 32, 32, 32, 32] fp32.  Flat offset = ((b*32+i)*32+j)*32+k)*32+c
//   = b*2^20 + i*32768 + j*1024 + k*32 + c
// W: [32, 256] row-major (o, 8 sections of 32 channels), b: [32]
// out[b,i,j,k,o] = W0.x + B1[b,j,k] + B2[b,i,k] + A3[b,i,j]

__global__ __launch_bounds__(256) void reduce_kernel(
    const float* __restrict__ x, float* __restrict__ S1,
    float* __restrict__ S2, float* __restrict__ S3) {
  const int seg = blockIdx.x >> 8;      // 0:S1(sum i) 1:S2(sum j) 2:S3(sum k)
  const int idx = blockIdx.x & 255;
  const int b = idx >> 5, a = idx & 31;
  const int t = threadIdx.x;
  const float* xb = x + ((size_t)b << 20);
  float acc0 = 0.f, acc1 = 0.f, acc2 = 0.f, acc3 = 0.f;
  float* dst;
  if (seg == 0) {
    // S1[b, j=a, k, c] = sum_i x[b,i,a,k,c]; flat (k*32+c) = t + 256*m
    const float* base = xb + a * 1024;
    for (int i = 0; i < 32; ++i) {
      const float* p = base + i * 32768;
      acc0 += p[t]; acc1 += p[t + 256]; acc2 += p[t + 512]; acc3 += p[t + 768];
    }
    dst = S1 + (size_t)(b * 32 + a) * 1024;
  } else if (seg == 1) {
    // S2[b, i=a, k, c] = sum_j
    const float* base = xb + a * 32768;
    for (int j = 0; j < 32; ++j) {
      const float* p = base + j * 1024;
      acc0 += p[t]; acc1 += p[t + 256]; acc2 += p[t + 512]; acc3 += p[t + 768];
    }
    dst = S2 + (size_t)(b * 32 + a) * 1024;
  } else {
    // S3[b, i=a, j, c] = sum_k; flat (j*32+c): j = (t>>5) + 8m, c = t&31
    const float* base = xb + a * 32768;
    const int j0 = t >> 5, c = t & 31;
    for (int k = 0; k < 32; ++k) {
      const int kk = k * 32 + c;
      acc0 += base[(j0     ) * 1024 + kk];
      acc1 += base[(j0 +  8) * 1024 + kk];
      acc2 += base[(j0 + 16) * 1024 + kk];
      acc3 += base[(j0 + 24) * 1024 + kk];
    }
    dst = S3 + (size_t)(b * 32 + a) * 1024;
  }
  dst[t] = acc0; dst[t + 256] = acc1; dst[t + 512] = acc2; dst[t + 768] = acc3;
}

__global__ __launch_bounds__(1024) void small_kernel(
    const float* __restrict__ S1, const float* __restrict__ S2,
    const float* __restrict__ S3, const float* __restrict__ W,
    const float* __restrict__ bias, float* __restrict__ B1,
    float* __restrict__ B2, float* __restrict__ A3o,
    float* __restrict__ W0t) {
  __shared__ float sWt[8192];                    // sWt[s*1024 + c*32 + o]
  __shared__ float sS12[1024], sS13[1024], sS23[1024];
  __shared__ float sA12[1024], sA13[1024], sA23[1024];
  __shared__ float sS123[32], sA123[32];
  const int b = blockIdx.x;
  const int t = threadIdx.x;
  const float* S1b = S1 + (size_t)b * 32768;
  const float* S2b = S2 + (size_t)b * 32768;
  const float* S3b = S3 + (size_t)b * 32768;

  // stage transposed W: sWt[s*1024 + c*32 + o] = W[o*256 + s*32 + c]
  #pragma unroll
  for (int m = 0; m < 8; ++m) {
    const int f = t + m * 1024;
    const int s = f >> 10, rem = f & 1023, c = rem >> 5, o = rem & 31;
    sWt[f] = W[o * 256 + s * 32 + c];
  }
  if (b == 0) W0t[t] = W[(t & 31) * 256 + (t >> 5)];   // W0t[c*32+o]

  {   // S12[k,c] = sum_j S1[b,j,k,c]; flat t = k*32+c
    float s = 0.f;
    for (int j = 0; j < 32; ++j) s += S1b[j * 1024 + t];
    sS12[t] = s;
  }
  {   // S13[j,c] = sum_k S1;  S23[i,c] = sum_k S2 ; flat t = (j|i)*32+c
    const int j = t >> 5, c = t & 31;
    float s = 0.f, s2 = 0.f;
    for (int k = 0; k < 32; ++k) {
      s  += S1b[j * 1024 + k * 32 + c];
      s2 += S2b[j * 1024 + k * 32 + c];
    }
    sS13[t] = s;
    sS23[t] = s2;
  }
  __syncthreads();
  if (t < 32) {  // S123[c] = sum_k S12[k,c]
    float s = 0.f;
    for (int k = 0; k < 32; ++k) s += sS12[k * 32 + t];
    sS123[t] = s;
  }
  {   // A12[k,o], A13[j,o], A23[i,o];  flat t = (k|j|i)*32 + o
    const int k = t >> 5, o = t & 31;
    float s = 0.f, s2 = 0.f, s3 = 0.f;
    for (int c = 0; c < 32; ++c) {
      s  += sWt[4 * 1024 + c * 32 + o] * sS12[k * 32 + c];
      s2 += sWt[5 * 1024 + c * 32 + o] * sS13[k * 32 + c];
      s3 += sWt[6 * 1024 + c * 32 + o] * sS23[k * 32 + c];
    }
    sA12[t] = s  * (1.f / 1024.f);
    sA13[t] = s2 * (1.f / 1024.f);
    sA23[t] = s3 * (1.f / 1024.f);
  }
  __syncthreads();
  if (t < 32) {  // A123[o]
    float s = 0.f;
    for (int c = 0; c < 32; ++c) s += sWt[7 * 1024 + c * 32 + t] * sS123[c];
    sA123[t] = s * (1.f / 32768.f);
  }
  __syncthreads();

  float* B1b = B1  + (size_t)b * 32768;
  float* B2b = B2  + (size_t)b * 32768;
  float* A3b = A3o + (size_t)b * 32768;
  const int k = t >> 5, o = t & 31;   // t = k*32 + o
  const float biasv = bias[o];
  const float a123 = sA123[o];
  const float a12  = sA12[k * 32 + o];
  for (int m = 0; m < 32; ++m) {      // m plays j (B1) or i (B2, A3)
    const float* p1 = S1b + m * 1024 + k * 32;
    const float* p2 = S2b + m * 1024 + k * 32;
    const float* p3 = S3b + m * 1024 + k * 32;
    float s1 = 0.f, s2 = 0.f, s3 = 0.f;
    #pragma unroll
    for (int c = 0; c < 32; ++c) {
      s1 += sWt[1 * 1024 + c * 32 + o] * p1[c];
      s2 += sWt[2 * 1024 + c * 32 + o] * p2[c];
      s3 += sWt[3 * 1024 + c * 32 + o] * p3[c];
    }
    B1b[m * 1024 + t] = s1 * (1.f / 32.f) + a12 + sA13[m * 32 + o] + a123 + biasv;
    B2b[m * 1024 + t] = s2 * (1.f / 32.f) + sA23[m * 32 + o];
    A3b[m * 1024 + t] = s3 * (1.f / 32.f);
  }
}

__global__ __launch_bounds__(256) void final_kernel(
    const float* __restrict__ x, const float* __restrict__ W0t,
    const float* __restrict__ B1, const float* __restrict__ B2,
    const float* __restrict__ A3o, float* __restrict__ out) {
  __shared__ float xs[256 * 33];   // +1 pad: bank (t+c)%32, conflict-free
  __shared__ float wt[1024];       // wt[c*32+o]
  const int t = threadIdx.x;
  const size_t pos0 = (size_t)blockIdx.x * 256;

  // coalesced x tile load (8192 floats)
  const float* xp = x + pos0 * 32;
  #pragma unroll
  for (int m = 0; m < 32; ++m) {
    const int f = t + 256 * m;
    xs[(f >> 5) * 33 + (f & 31)] = xp[f];
  }
  #pragma unroll
  for (int m = 0; m < 4; ++m) wt[t + 256 * m] = W0t[t + 256 * m];
  __syncthreads();

  const size_t p = pos0 + t;
  const int k = (int)(p & 31), j = (int)(p >> 5) & 31,
            i = (int)(p >> 10) & 31, b = (int)(p >> 15);
  const float* b1 = B1  + ((size_t)((b * 32 + j) * 32 + k)) * 32;
  const float* b2 = B2  + ((size_t)((b * 32 + i) * 32 + k)) * 32;
  const float* a3 = A3o + ((size_t)((b * 32 + i) * 32 + j)) * 32;

  float acc[32];
  #pragma unroll
  for (int o4 = 0; o4 < 8; ++o4) {
    const float4 v1 = ((const float4*)b1)[o4];
    const float4 v2 = ((const float4*)b2)[o4];
    const float4 v3 = ((const float4*)a3)[o4];
    acc[o4 * 4 + 0] = v1.x + v2.x + v3.x;
    acc[o4 * 4 + 1] = v1.y + v2.y + v3.y;
    acc[o4 * 4 + 2] = v1.z + v2.z + v3.z;
    acc[o4 * 4 + 3] = v1.w + v2.w + v3.w;
  }

  const float4* wt4 = (const float4*)wt;
  #pragma unroll
  for (int c = 0; c < 32; ++c) {
    const float xv = xs[t * 33 + c];
    #pragma unroll
    for (int o4 = 0; o4 < 8; ++o4) {
      const float4 w = wt4[c * 8 + o4];   // broadcast read, conflict-free
      acc[o4 * 4 + 0] += xv * w.x;
      acc[o4 * 4 + 1] += xv * w.y;
      acc[o4 * 4 + 2] += xv * w.z;
      acc[o4 * 4 + 3] += xv * w.w;
    }
  }

  // transpose through LDS for coalesced stores
  __syncthreads();
  #pragma unroll
  for (int o = 0; o < 32; ++o) xs[t * 33 + o] = acc[o];
  __syncthreads();
  float* op = out + pos0 * 32;
  #pragma unroll
  for (int m = 0; m < 32; ++m) {
    const int f = t + 256 * m;
    op[f] = xs[(f >> 5) * 33 + (f & 31)];
  }
}

extern "C" void kernel_launch(void* const* d_in, const int* in_sizes, int n_in,
                              void* d_out, int out_size, void* d_ws, size_t ws_size,
                              hipStream_t stream) {
  const float* x    = (const float*)d_in[0];
  const float* W    = (const float*)d_in[1];
  const float* bias = (const float*)d_in[2];
  float* out = (float*)d_out;
  float* ws  = (float*)d_ws;
  // workspace layout (floats): S1,S2,S3,B1,B2,A3o each 262144; W0t 1024
  float* S1  = ws;
  float* S2  = ws + 262144;
  float* S3  = ws + 524288;
  float* B1  = ws + 786432;
  float* B2  = ws + 1048576;
  float* A3o = ws + 1310720;
  float* W0t = ws + 1572864;

  reduce_kernel<<<768, 256, 0, stream>>>(x, S1, S2, S3);
  small_kernel<<<8, 1024, 0, stream>>>(S1, S2, S3, W, bias, B1, B2, A3o, W0t);
  final_kernel<<<1024, 256, 0, stream>>>(x, W0t, B1, B2, A3o, out);
}

// Round 3
// 140.505 us; speedup vs baseline: 4.2719x; 4.2719x over previous
//
#include <hip/hip_runtime.h>

// x: [8, 32, 32, 32, 32] fp32.  Flat offset = b*2^20 + i*32768 + j*1024 + k*32 + c
// W: [32, 256] row-major (o, 8 sections of 32 channels). Sections:
//   0:x 1:mean_i 2:mean_j 3:mean_k 4:mean_ij 5:mean_ik 6:mean_jk 7:mean_ijk
// out[b,i,j,k,o] = W0.x + B1[b,j,k,o] + B2[b,i,k,o] + A3[b,i,j,o]
//   B1 = W1.m1 + a12 + a13 + a123 + bias;  B2 = W2.m2 + a23;  A3 = W3.m3

__global__ __launch_bounds__(256) void reduce_kernel(
    const float* __restrict__ x, float* __restrict__ S1,
    float* __restrict__ S2, float* __restrict__ S3) {
  const int seg = blockIdx.x >> 8;      // 0:S1(sum i) 1:S2(sum j) 2:S3(sum k)
  const int idx = blockIdx.x & 255;
  const int b = idx >> 5, a = idx & 31;
  const int t = threadIdx.x;
  const float* xb = x + ((size_t)b << 20);
  float acc0 = 0.f, acc1 = 0.f, acc2 = 0.f, acc3 = 0.f;
  float* dst;
  if (seg == 0) {
    // S1[b, j=a, k, c] = sum_i x[b,i,a,k,c]
    const float* base = xb + a * 1024;
    for (int i = 0; i < 32; ++i) {
      const float* p = base + i * 32768;
      acc0 += p[t]; acc1 += p[t + 256]; acc2 += p[t + 512]; acc3 += p[t + 768];
    }
    dst = S1 + (size_t)(b * 32 + a) * 1024;
  } else if (seg == 1) {
    // S2[b, i=a, k, c] = sum_j
    const float* base = xb + a * 32768;
    for (int j = 0; j < 32; ++j) {
      const float* p = base + j * 1024;
      acc0 += p[t]; acc1 += p[t + 256]; acc2 += p[t + 512]; acc3 += p[t + 768];
    }
    dst = S2 + (size_t)(b * 32 + a) * 1024;
  } else {
    // S3[b, i=a, j, c] = sum_k
    const float* base = xb + a * 32768;
    const int j0 = t >> 5, c = t & 31;
    for (int k = 0; k < 32; ++k) {
      const int kk = k * 32 + c;
      acc0 += base[(j0     ) * 1024 + kk];
      acc1 += base[(j0 +  8) * 1024 + kk];
      acc2 += base[(j0 + 16) * 1024 + kk];
      acc3 += base[(j0 + 24) * 1024 + kk];
    }
    dst = S3 + (size_t)(b * 32 + a) * 1024;
  }
  dst[t] = acc0; dst[t + 256] = acc1; dst[t + 512] = acc2; dst[t + 768] = acc3;
}

// Second-level pools + A-tables. grid = 24: blockIdx = seg*8 + b.
//  seg0: S12[b,k,c]=sum_j S1 -> A12[b,k,o]; S123[b,c] -> A123[b,o]
//  seg1: S13[b,j,c]=sum_k S1 -> A13[b,j,o]
//  seg2: S23[b,i,c]=sum_k S2 -> A23[b,i,o]
__global__ __launch_bounds__(256) void pool_kernel(
    const float* __restrict__ S1, const float* __restrict__ S2,
    const float* __restrict__ W, float* __restrict__ A12g,
    float* __restrict__ A13g, float* __restrict__ A23g,
    float* __restrict__ A123g) {
  __shared__ float sBuf[1024];   // S12/S13/S23 for this b
  __shared__ float sW[1024];     // section (4|5|6) transposed: [c*32+o]
  __shared__ float sW7[1024];    // section 7 transposed (seg0 only)
  __shared__ float sS123[32];
  const int seg = blockIdx.x >> 3;
  const int b = blockIdx.x & 7;
  const int t = threadIdx.x;
  const int sec = 4 + seg;       // W section for the A-table

  #pragma unroll
  for (int m = 0; m < 4; ++m) {
    const int e = t + 256 * m, c = e >> 5, o = e & 31;
    sW[e] = W[o * 256 + sec * 32 + c];
    if (seg == 0) sW7[e] = W[o * 256 + 7 * 32 + c];
  }

  const float* Sb = ((seg == 2) ? S2 : S1) + (size_t)b * 32768;
  #pragma unroll
  for (int m = 0; m < 4; ++m) {
    const int e = t + 256 * m, a = e >> 5, c = e & 31;
    float s = 0.f;
    if (seg == 0) {             // S12[k=a,c] = sum_j S1[b,j,a_k,c]
      for (int j = 0; j < 32; ++j) s += Sb[j * 1024 + a * 32 + c];
    } else {                    // S13/S23[(j|i)=a,c] = sum_k
      for (int k = 0; k < 32; ++k) s += Sb[a * 1024 + k * 32 + c];
    }
    sBuf[e] = s;
  }
  __syncthreads();

  if (seg == 0 && t < 32) {     // S123[c=t]
    float s = 0.f;
    for (int k = 0; k < 32; ++k) s += sBuf[k * 32 + t];
    sS123[t] = s;
  }
  __syncthreads();

  float* Ag = (seg == 0) ? A12g : (seg == 1) ? A13g : A23g;
  #pragma unroll
  for (int m = 0; m < 4; ++m) {
    const int e = t + 256 * m, a = e >> 5, o = e & 31;
    float s = 0.f;
    #pragma unroll
    for (int c = 0; c < 32; ++c) s += sW[c * 32 + o] * sBuf[a * 32 + c];
    Ag[b * 1024 + e] = s * (1.f / 1024.f);
  }
  if (seg == 0 && t < 32) {     // A123[o=t]
    float s = 0.f;
    #pragma unroll
    for (int c = 0; c < 32; ++c) s += sW7[c * 32 + t] * sS123[c];
    A123g[b * 32 + t] = s * (1.f / 32768.f);
  }
}

// Three [8192x32]x[32x32] GEMMs producing B1, B2, A3 (+ epilogue consts).
// grid = 96: seg = blockIdx>>5, 256 rows per block.
__global__ __launch_bounds__(256) void bigB_kernel(
    const float* __restrict__ S1, const float* __restrict__ S2,
    const float* __restrict__ S3, const float* __restrict__ W,
    const float* __restrict__ bias, const float* __restrict__ A12g,
    const float* __restrict__ A13g, const float* __restrict__ A23g,
    const float* __restrict__ A123g, float* __restrict__ B1,
    float* __restrict__ B2, float* __restrict__ A3o,
    float* __restrict__ W0t) {
  __shared__ float xs[256 * 33];
  __shared__ float wt[1024];     // section seg+1 transposed [c*32+o]
  const int seg = blockIdx.x >> 5;
  const int r0 = (blockIdx.x & 31) * 256;
  const int t = threadIdx.x;
  const float* src = (seg == 0) ? S1 : (seg == 1) ? S2 : S3;
  float* dst = (seg == 0) ? B1 : (seg == 1) ? B2 : A3o;

  const float* sp = src + (size_t)r0 * 32;
  #pragma unroll
  for (int m = 0; m < 32; ++m) {
    const int f = t + 256 * m;
    xs[(f >> 5) * 33 + (f & 31)] = sp[f];
  }
  #pragma unroll
  for (int m = 0; m < 4; ++m) {
    const int e = t + 256 * m;
    wt[e] = W[(e & 31) * 256 + (seg + 1) * 32 + (e >> 5)];
  }
  if (blockIdx.x == 0) {
    // W0t[c*32+o] = W[o*256 + c] — FIX(R3): 256 threads must cover all
    // 1024 entries (R2 wrote only the first 256 -> 3/4 poison -> absmax 1.0)
    #pragma unroll
    for (int m = 0; m < 4; ++m) {
      const int e = t + 256 * m;
      W0t[e] = W[(e & 31) * 256 + (e >> 5)];
    }
  }
  __syncthreads();

  float acc[32];
  #pragma unroll
  for (int o = 0; o < 32; ++o) acc[o] = 0.f;
  const float4* wt4 = (const float4*)wt;
  #pragma unroll
  for (int c = 0; c < 32; ++c) {
    const float xv = xs[t * 33 + c];
    #pragma unroll
    for (int o4 = 0; o4 < 8; ++o4) {
      const float4 w = wt4[c * 8 + o4];
      acc[o4 * 4 + 0] += xv * w.x;
      acc[o4 * 4 + 1] += xv * w.y;
      acc[o4 * 4 + 2] += xv * w.z;
      acc[o4 * 4 + 3] += xv * w.w;
    }
  }
  #pragma unroll
  for (int o = 0; o < 32; ++o) acc[o] *= (1.f / 32.f);

  // epilogue additive constants
  const int r = r0 + t;
  const int b = r >> 10, mm = (r >> 5) & 31, k = r & 31;
  if (seg == 0) {               // + a12[b,k,o] + a13[b,j,o] + a123[b,o] + bias
    const float4* p12 = (const float4*)(A12g + (size_t)(b * 32 + k) * 32);
    const float4* p13 = (const float4*)(A13g + (size_t)(b * 32 + mm) * 32);
    const float4* p123 = (const float4*)(A123g + (size_t)b * 32);
    const float4* pb = (const float4*)bias;
    #pragma unroll
    for (int o4 = 0; o4 < 8; ++o4) {
      const float4 v1 = p12[o4], v2 = p13[o4], v3 = p123[o4], v4 = pb[o4];
      acc[o4 * 4 + 0] += v1.x + v2.x + v3.x + v4.x;
      acc[o4 * 4 + 1] += v1.y + v2.y + v3.y + v4.y;
      acc[o4 * 4 + 2] += v1.z + v2.z + v3.z + v4.z;
      acc[o4 * 4 + 3] += v1.w + v2.w + v3.w + v4.w;
    }
  } else if (seg == 1) {        // + a23[b,i,o]
    const float4* p23 = (const float4*)(A23g + (size_t)(b * 32 + mm) * 32);
    #pragma unroll
    for (int o4 = 0; o4 < 8; ++o4) {
      const float4 v = p23[o4];
      acc[o4 * 4 + 0] += v.x; acc[o4 * 4 + 1] += v.y;
      acc[o4 * 4 + 2] += v.z; acc[o4 * 4 + 3] += v.w;
    }
  }

  __syncthreads();
  #pragma unroll
  for (int o = 0; o < 32; ++o) xs[t * 33 + o] = acc[o];
  __syncthreads();
  float* op = dst + (size_t)r0 * 32;
  #pragma unroll
  for (int m = 0; m < 32; ++m) {
    const int f = t + 256 * m;
    op[f] = xs[(f >> 5) * 33 + (f & 31)];
  }
}

__global__ __launch_bounds__(256) void final_kernel(
    const float* __restrict__ x, const float* __restrict__ W0t,
    const float* __restrict__ B1, const float* __restrict__ B2,
    const float* __restrict__ A3o, float* __restrict__ out) {
  __shared__ float xs[256 * 33];
  __shared__ float wt[1024];
  const int t = threadIdx.x;
  const size_t pos0 = (size_t)blockIdx.x * 256;

  const float* xp = x + pos0 * 32;
  #pragma unroll
  for (int m = 0; m < 32; ++m) {
    const int f = t + 256 * m;
    xs[(f >> 5) * 33 + (f & 31)] = xp[f];
  }
  #pragma unroll
  for (int m = 0; m < 4; ++m) wt[t + 256 * m] = W0t[t + 256 * m];
  __syncthreads();

  const size_t p = pos0 + t;
  const int k = (int)(p & 31), j = (int)(p >> 5) & 31,
            i = (int)(p >> 10) & 31, b = (int)(p >> 15);
  const float* b1 = B1  + ((size_t)((b * 32 + j) * 32 + k)) * 32;
  const float* b2 = B2  + ((size_t)((b * 32 + i) * 32 + k)) * 32;
  const float* a3 = A3o + ((size_t)((b * 32 + i) * 32 + j)) * 32;

  float acc[32];
  #pragma unroll
  for (int o4 = 0; o4 < 8; ++o4) {
    const float4 v1 = ((const float4*)b1)[o4];
    const float4 v2 = ((const float4*)b2)[o4];
    const float4 v3 = ((const float4*)a3)[o4];
    acc[o4 * 4 + 0] = v1.x + v2.x + v3.x;
    acc[o4 * 4 + 1] = v1.y + v2.y + v3.y;
    acc[o4 * 4 + 2] = v1.z + v2.z + v3.z;
    acc[o4 * 4 + 3] = v1.w + v2.w + v3.w;
  }

  const float4* wt4 = (const float4*)wt;
  #pragma unroll
  for (int c = 0; c < 32; ++c) {
    const float xv = xs[t * 33 + c];
    #pragma unroll
    for (int o4 = 0; o4 < 8; ++o4) {
      const float4 w = wt4[c * 8 + o4];
      acc[o4 * 4 + 0] += xv * w.x;
      acc[o4 * 4 + 1] += xv * w.y;
      acc[o4 * 4 + 2] += xv * w.z;
      acc[o4 * 4 + 3] += xv * w.w;
    }
  }

  __syncthreads();
  #pragma unroll
  for (int o = 0; o < 32; ++o) xs[t * 33 + o] = acc[o];
  __syncthreads();
  float* op = out + pos0 * 32;
  #pragma unroll
  for (int m = 0; m < 32; ++m) {
    const int f = t + 256 * m;
    op[f] = xs[(f >> 5) * 33 + (f & 31)];
  }
}

extern "C" void kernel_launch(void* const* d_in, const int* in_sizes, int n_in,
                              void* d_out, int out_size, void* d_ws, size_t ws_size,
                              hipStream_t stream) {
  const float* x    = (const float*)d_in[0];
  const float* W    = (const float*)d_in[1];
  const float* bias = (const float*)d_in[2];
  float* out = (float*)d_out;
  float* ws  = (float*)d_ws;
  // workspace layout (floats)
  float* S1    = ws;                // 262144
  float* S2    = ws + 262144;       // 262144
  float* S3    = ws + 524288;       // 262144
  float* B1    = ws + 786432;       // 262144
  float* B2    = ws + 1048576;      // 262144
  float* A3o   = ws + 1310720;      // 262144
  float* W0t   = ws + 1572864;      // 1024
  float* A12g  = ws + 1573888;      // 8192
  float* A13g  = ws + 1582080;      // 8192
  float* A23g  = ws + 1590272;      // 8192
  float* A123g = ws + 1598464;      // 256

  reduce_kernel<<<768, 256, 0, stream>>>(x, S1, S2, S3);
  pool_kernel<<<24, 256, 0, stream>>>(S1, S2, W, A12g, A13g, A23g, A123g);
  bigB_kernel<<<96, 256, 0, stream>>>(S1, S2, S3, W, bias, A12g, A13g, A23g,
                                      A123g, B1, B2, A3o, W0t);
  final_kernel<<<1024, 256, 0, stream>>>(x, W0t, B1, B2, A3o, out);
}

// Round 4
// 115.051 us; speedup vs baseline: 5.2170x; 1.2212x over previous
//
#include <hip/hip_runtime.h>

// x: [8, 32, 32, 32, 32] fp32.  Flat = b*2^20 + i*32768 + j*1024 + k*32 + c
// W: [32, 256] row-major (o, 8 sections). Sections:
//   0:x 1:mean_i 2:mean_j 3:mean_k 4:mean_ij 5:mean_ik 6:mean_jk 7:mean_ijk
// out[b,i,j,k,o] = W0.x + B1[b,j,k,o] + B2[b,i,k,o] + A3[b,i,j,o]
//                + A12[b,k,o] + A13[b,j,o] + A23[b,i,o] + A123[b,o] + bias[o]
// (B/A tables are raw GEMM results; ALL small adds live in final's epilogue)

static __device__ __forceinline__ float4 f4add(float4 a, float4 b) {
  a.x += b.x; a.y += b.y; a.z += b.z; a.w += b.w; return a;
}

__global__ __launch_bounds__(256) void reduce_kernel(
    const float* __restrict__ x, float* __restrict__ S1,
    float* __restrict__ S2, float* __restrict__ S3) {
  const int seg = blockIdx.x >> 8;      // 0:S1(sum i) 1:S2(sum j) 2:S3(sum k)
  const int idx = blockIdx.x & 255;
  const int b = idx >> 5, a = idx & 31;
  const int t = threadIdx.x;
  const float* xb = x + ((size_t)b << 20);
  float4 acc = make_float4(0.f, 0.f, 0.f, 0.f);
  float* dst;
  if (seg == 0) {
    // S1[b, j=a, k, c] = sum_i x[b,i,a,k,c]; thread owns floats 4t..4t+3 of [k,c]
    const float* base = xb + a * 1024 + 4 * t;
    #pragma unroll
    for (int i = 0; i < 32; ++i) acc = f4add(acc, *(const float4*)(base + i * 32768));
    dst = S1 + (size_t)(b * 32 + a) * 1024;
  } else if (seg == 1) {
    // S2[b, i=a, k, c] = sum_j
    const float* base = xb + a * 32768 + 4 * t;
    #pragma unroll
    for (int j = 0; j < 32; ++j) acc = f4add(acc, *(const float4*)(base + j * 1024));
    dst = S2 + (size_t)(b * 32 + a) * 1024;
  } else {
    // S3[b, i=a, j, c] = sum_k; thread owns flat (j*32+c) 4t..4t+3
    const float* base = xb + a * 32768 + (t >> 3) * 1024 + 4 * (t & 7);
    #pragma unroll
    for (int k = 0; k < 32; ++k) acc = f4add(acc, *(const float4*)(base + k * 32));
    dst = S3 + (size_t)(b * 32 + a) * 1024;
  }
  ((float4*)dst)[t] = acc;
}

// Merged: blocks 0..95 = three [8192x32]x[32x32] GEMMs (B1,B2,A3, scaled 1/32);
//         blocks 96..119 = second-level pools -> A12/A13/A23/A123 tables.
// Independent: bigB no longer consumes A-tables (final adds them).
__global__ __launch_bounds__(256) void mid_kernel(
    const float* __restrict__ S1, const float* __restrict__ S2,
    const float* __restrict__ S3, const float* __restrict__ W,
    float* __restrict__ B1, float* __restrict__ B2, float* __restrict__ A3o,
    float* __restrict__ A12g, float* __restrict__ A13g,
    float* __restrict__ A23g, float* __restrict__ A123g,
    float* __restrict__ W0t) {
  __shared__ float smem[9472];
  const int t = threadIdx.x;
  if (blockIdx.x < 96) {
    float* xs = smem;            // [256][33]
    float* wt = smem + 8448;     // W section seg+1 transposed [c*32+o]
    const int seg = blockIdx.x >> 5;
    const int r0 = (blockIdx.x & 31) * 256;
    const float* src = (seg == 0) ? S1 : (seg == 1) ? S2 : S3;
    float* dst = (seg == 0) ? B1 : (seg == 1) ? B2 : A3o;

    const float4* sp4 = (const float4*)(src + (size_t)r0 * 32);
    #pragma unroll
    for (int m = 0; m < 8; ++m) {
      const int q = t + 256 * m;          // float4 index; element e = 4q
      const float4 v = sp4[q];
      const int row = q >> 3, c0 = 4 * (q & 7);
      float* p = xs + row * 33 + c0;
      p[0] = v.x; p[1] = v.y; p[2] = v.z; p[3] = v.w;
    }
    #pragma unroll
    for (int m = 0; m < 4; ++m) {
      const int e = t + 256 * m;
      wt[e] = W[(e & 31) * 256 + (seg + 1) * 32 + (e >> 5)];
    }
    if (blockIdx.x == 0) {
      #pragma unroll
      for (int m = 0; m < 4; ++m) {
        const int e = t + 256 * m;
        W0t[e] = W[(e & 31) * 256 + (e >> 5)];   // W0t[c*32+o]
      }
    }
    __syncthreads();

    float acc[32];
    #pragma unroll
    for (int o = 0; o < 32; ++o) acc[o] = 0.f;
    const float4* wt4 = (const float4*)wt;
    #pragma unroll
    for (int c = 0; c < 32; ++c) {
      const float xv = xs[t * 33 + c];
      #pragma unroll
      for (int o4 = 0; o4 < 8; ++o4) {
        const float4 w = wt4[c * 8 + o4];
        acc[o4 * 4 + 0] += xv * w.x;
        acc[o4 * 4 + 1] += xv * w.y;
        acc[o4 * 4 + 2] += xv * w.z;
        acc[o4 * 4 + 3] += xv * w.w;
      }
    }
    __syncthreads();
    #pragma unroll
    for (int o = 0; o < 32; ++o) xs[t * 33 + o] = acc[o] * (1.f / 32.f);
    __syncthreads();
    float* op = dst + (size_t)r0 * 32;
    #pragma unroll
    for (int m = 0; m < 32; ++m) {
      const int f = t + 256 * m;
      op[f] = xs[(f >> 5) * 33 + (f & 31)];
    }
  } else {
    // pool: blk = seg*8 + b
    const int blk = blockIdx.x - 96;
    const int seg = blk >> 3, b = blk & 7;
    float* sBuf  = smem;          // [32][32] second-level sums
    float* sW    = smem + 1024;   // section 4+seg transposed [c*32+o]
    float* sW7   = smem + 2048;   // section 7 transposed
    float* sS123 = smem + 3072;   // [32]
    const int sec = 4 + seg;

    #pragma unroll
    for (int m = 0; m < 4; ++m) {
      const int e = t + 256 * m, c = e >> 5, o = e & 31;
      sW[e] = W[o * 256 + sec * 32 + c];
      if (seg == 0) sW7[e] = W[o * 256 + 7 * 32 + c];
    }
    const float* Sb = ((seg == 2) ? S2 : S1) + (size_t)b * 32768;
    #pragma unroll
    for (int m = 0; m < 4; ++m) {
      const int e = t + 256 * m, a = e >> 5, c = e & 31;
      float s = 0.f;
      if (seg == 0) {            // S12[k=a,c] = sum_j S1[b,j,a,c]
        for (int j = 0; j < 32; ++j) s += Sb[j * 1024 + a * 32 + c];
      } else {                   // S13/S23[(j|i)=a,c] = sum_k
        for (int k = 0; k < 32; ++k) s += Sb[a * 1024 + k * 32 + c];
      }
      sBuf[e] = s;
    }
    __syncthreads();
    if (seg == 0 && t < 32) {
      float s = 0.f;
      for (int k = 0; k < 32; ++k) s += sBuf[k * 32 + t];
      sS123[t] = s;
    }
    __syncthreads();
    float* Ag = (seg == 0) ? A12g : (seg == 1) ? A13g : A23g;
    #pragma unroll
    for (int m = 0; m < 4; ++m) {
      const int e = t + 256 * m, a = e >> 5, o = e & 31;
      float s = 0.f;
      #pragma unroll
      for (int c = 0; c < 32; ++c) s += sW[c * 32 + o] * sBuf[a * 32 + c];
      Ag[b * 1024 + e] = s * (1.f / 1024.f);
    }
    if (seg == 0 && t < 32) {
      float s = 0.f;
      #pragma unroll
      for (int c = 0; c < 32; ++c) s += sW7[c * 32 + t] * sS123[c];
      A123g[b * 32 + t] = s * (1.f / 32768.f);
    }
  }
}

__global__ __launch_bounds__(256) void final_kernel(
    const float* __restrict__ x, const float* __restrict__ W0t,
    const float* __restrict__ B1, const float* __restrict__ B2,
    const float* __restrict__ A3o, const float* __restrict__ A12g,
    const float* __restrict__ A13g, const float* __restrict__ A23g,
    const float* __restrict__ A123g, const float* __restrict__ bias,
    float* __restrict__ out) {
  __shared__ float xs[256 * 33];
  __shared__ float wt[1024];     // W0 transposed [c*32+o]
  const int t = threadIdx.x;
  const size_t pos0 = (size_t)blockIdx.x * 256;

  // stage x tile: float4 global loads, scalar LDS writes (stride 33, ~2-way)
  const float4* xp4 = (const float4*)(x + pos0 * 32);
  #pragma unroll
  for (int m = 0; m < 8; ++m) {
    const int q = t + 256 * m;
    const float4 v = xp4[q];
    const int row = q >> 3, c0 = 4 * (q & 7);
    float* p = xs + row * 33 + c0;
    p[0] = v.x; p[1] = v.y; p[2] = v.z; p[3] = v.w;
  }
  #pragma unroll
  for (int m = 0; m < 4; ++m) wt[t + 256 * m] = W0t[t + 256 * m];
  __syncthreads();

  // thread = (rg = t>>2: 4 consecutive rows, og = t&3: 8 consecutive outs)
  const int rg = t >> 2, og = t & 3;
  const int lrow0 = 4 * rg;             // local rows lrow0..lrow0+3
  const size_t p0 = pos0 + lrow0;       // rows share b,i,j (4-aligned in k)
  const int k0 = (int)(p0 & 31), j = (int)(p0 >> 5) & 31,
            i = (int)(p0 >> 10) & 31, b = (int)(p0 >> 15);

  float acc[4][8];
  #pragma unroll
  for (int r = 0; r < 4; ++r)
    #pragma unroll
    for (int u = 0; u < 8; ++u) acc[r][u] = 0.f;

  const float4* wt4 = (const float4*)wt;
  #pragma unroll
  for (int c = 0; c < 32; ++c) {
    const float4 w0 = wt4[c * 8 + og * 2];
    const float4 w1 = wt4[c * 8 + og * 2 + 1];
    #pragma unroll
    for (int r = 0; r < 4; ++r) {
      const float xv = xs[(lrow0 + r) * 33 + c];
      acc[r][0] += xv * w0.x; acc[r][1] += xv * w0.y;
      acc[r][2] += xv * w0.z; acc[r][3] += xv * w0.w;
      acc[r][4] += xv * w1.x; acc[r][5] += xv * w1.y;
      acc[r][6] += xv * w1.z; acc[r][7] += xv * w1.w;
    }
  }

  // epilogue: row-invariant combo once, per-row B1/B2/A12 (k = k0+r)
  const int oo = og * 8;                // first of this thread's 8 outputs
  const float* a3  = A3o  + ((size_t)((b * 32 + i) * 32 + j)) * 32 + oo;
  const float* a13 = A13g + (size_t)(b * 32 + j) * 32 + oo;
  const float* a23 = A23g + (size_t)(b * 32 + i) * 32 + oo;
  const float* a123 = A123g + (size_t)b * 32 + oo;
  const float* bi = bias + oo;
  float inv[8];
  #pragma unroll
  for (int u = 0; u < 8; ++u) inv[u] = a3[u] + a13[u] + a23[u] + a123[u] + bi[u];

  #pragma unroll
  for (int r = 0; r < 4; ++r) {
    const int k = k0 + r;
    const float* b1  = B1   + ((size_t)((b * 32 + j) * 32 + k)) * 32 + oo;
    const float* b2  = B2   + ((size_t)((b * 32 + i) * 32 + k)) * 32 + oo;
    const float* a12 = A12g + (size_t)(b * 32 + k) * 32 + oo;
    #pragma unroll
    for (int u = 0; u < 8; ++u) acc[r][u] += inv[u] + b1[u] + b2[u] + a12[u];
  }

  // direct stores: 2 float4 per row
  #pragma unroll
  for (int r = 0; r < 4; ++r) {
    float4* op = (float4*)(out + (p0 + r) * 32 + oo);
    op[0] = make_float4(acc[r][0], acc[r][1], acc[r][2], acc[r][3]);
    op[1] = make_float4(acc[r][4], acc[r][5], acc[r][6], acc[r][7]);
  }
}

extern "C" void kernel_launch(void* const* d_in, const int* in_sizes, int n_in,
                              void* d_out, int out_size, void* d_ws, size_t ws_size,
                              hipStream_t stream) {
  const float* x    = (const float*)d_in[0];
  const float* W    = (const float*)d_in[1];
  const float* bias = (const float*)d_in[2];
  float* out = (float*)d_out;
  float* ws  = (float*)d_ws;
  float* S1    = ws;                // 262144
  float* S2    = ws + 262144;
  float* S3    = ws + 524288;
  float* B1    = ws + 786432;
  float* B2    = ws + 1048576;
  float* A3o   = ws + 1310720;
  float* W0t   = ws + 1572864;      // 1024
  float* A12g  = ws + 1573888;      // 8192
  float* A13g  = ws + 1582080;      // 8192
  float* A23g  = ws + 1590272;      // 8192
  float* A123g = ws + 1598464;      // 256

  reduce_kernel<<<768, 256, 0, stream>>>(x, S1, S2, S3);
  mid_kernel<<<120, 256, 0, stream>>>(S1, S2, S3, W, B1, B2, A3o,
                                      A12g, A13g, A23g, A123g, W0t);
  final_kernel<<<1024, 256, 0, stream>>>(x, W0t, B1, B2, A3o, A12g, A13g,
                                         A23g, A123g, bias, out);
}